// Round 5
// baseline (3229.162 us; speedup 1.0000x reference)
//
#include <hip/hip_runtime.h>

// LatentRecurrent persistent kernel v5: B=4096, Z=512, H=384, T=32, r=0.025
// v4 post-mortem: depth-3 circular prefetch with lookahead 3 -> (kk+3)%3 == kk%3,
// and the load was issued BEFORE the MFMA -> clobbered the fragment in use.
// v5 fixes the order: MFMA consumes slot kk%3, THEN the slot is refilled with
// fragment kk+3 (WAR dep keeps it correct; lookahead still 3 iterations).
// Kept from v4: __launch_bounds__(512,2) (256-VGPR budget; LDS already caps at
// 2 waves/SIMD so the v3 128-cap only caused scratch spills = 3.4GB FETCH),
// cross-phase priming of next phase's weight loads before each barrier,
// BM=16 -> 256 blocks, MFMA 16x16x32 f16, LDS-routed full-line out stores.
// MFMA 16x16x32 layouts: A: m=l&15, k=(l>>4)*8+j. B: n=l&15, same k.
// C/D: col=l&15, row=(l>>4)*4+reg   [measured m89]

typedef _Float16 f16;
typedef f16 f16x8 __attribute__((ext_vector_type(8)));
typedef float f32x4 __attribute__((ext_vector_type(4)));

#define ZD 512
#define HD 384
#define K2 768
#define TT 32
#define BM 16
#define LZ 516   // zf row stride (f32): 516 % 32 == 4 -> balanced banks for b128
#define LT 392   // tz/hb row stride (f16): 196 words % 32 == 4 -> balanced, 16B rows

__device__ __forceinline__ float lrelu(float x) { return x >= 0.f ? x : 0.01f * x; }

__global__ void cvt_f32_f16(const float* __restrict__ s, f16* __restrict__ d, int n) {
    for (int i = blockIdx.x * blockDim.x + threadIdx.x; i < n; i += gridDim.x * blockDim.x)
        d[i] = (f16)s[i];
}

__global__ __launch_bounds__(512, 2) void latrec(
    const float* __restrict__ z0g, const float* __restrict__ h0g,
    const f16* __restrict__ W1h, const f16* __restrict__ W2h, const f16* __restrict__ W3h,
    const float* __restrict__ b1g, const float* __restrict__ b2g, const float* __restrict__ b3g,
    float* __restrict__ out)
{
    __shared__ float zf[BM * LZ];      // 33 KB  z master (f32)
    __shared__ float z0c[BM * ZD];     // 32 KB  z0 copy for residual
    __shared__ f16 tz[BM * LT];        // 12.25 KB
    __shared__ f16 hb[2][BM * LT];     // 24.5 KB   -> 103.4 KB total, 1 block/CU

    const int tid = threadIdx.x;
    const int w = tid >> 6, l = tid & 63;
    const int lm = l & 15;          // m (A) / n (B) / col (C) within 16-tile
    const int k0 = (l >> 4) * 8;    // k-offset of this lane's fragment
    const int rg0 = (l >> 4) * 4;   // first C/D row of this lane group
    const int m0 = blockIdx.x * BM;

    // ---- init: z into zf + z0c, zero out[:,0,:] ----
    for (int i = tid; i < BM * 128; i += 512) {
        int r = i >> 7, c = (i & 127) << 2;
        f32x4 v = *(const f32x4*)(z0g + (size_t)(m0 + r) * ZD + c);
        *(f32x4*)(zf + r * LZ + c) = v;
        *(f32x4*)(z0c + r * ZD + c) = v;
        f32x4 zr = {0.f, 0.f, 0.f, 0.f};
        __builtin_nontemporal_store(zr, (f32x4*)(out + (size_t)(m0 + r) * TT * ZD + c));
    }

    // ---- per-lane tile columns / biases / pointers / h state ----
    // GEMM1: wave w owns n-tiles {w, w+8, w+16} of 24 (N=384)
    // GEMM2/3: z-tiles {w, w+8, w+16, w+24} of 32 (N=512), h-tiles {w, w+8, w+16} of 24
    int c1[3], cz[4], ch[3];
    float bv1[3], bvz[4], bvh[3];
    float hreg[3][4];
    const f16* w1p[3];
    const f16* wp[7];
    #pragma unroll
    for (int j = 0; j < 3; ++j) {
        c1[j] = (w + 8 * j) * 16 + lm;
        bv1[j] = b1g[c1[j]];
        w1p[j] = W1h + (size_t)c1[j] * ZD + k0;
    }
    #pragma unroll
    for (int i = 0; i < 4; ++i) {
        cz[i] = (w + 8 * i) * 16 + lm;
        bvz[i] = b2g[cz[i]];
        wp[i] = W2h + (size_t)cz[i] * K2 + k0;
    }
    #pragma unroll
    for (int i = 0; i < 3; ++i) {
        ch[i] = (w + 8 * i) * 16 + lm;
        bvh[i] = b3g[ch[i]];
        wp[4 + i] = W3h + (size_t)ch[i] * K2 + k0;
        #pragma unroll
        for (int r = 0; r < 4; ++r) {
            int row = rg0 + r;
            float hv = h0g[(size_t)(m0 + row) * HD + ch[i]];
            hreg[i][r] = hv;
            hb[0][row * LT + ch[i]] = (f16)hv;
        }
    }
    __syncthreads();

    // ---- prime GEMM1 pipe for t=1 (slots 0..2 = fragments 0..2) ----
    f16x8 b1[3][3];
    #pragma unroll
    for (int q = 0; q < 3; ++q)
        #pragma unroll
        for (int j = 0; j < 3; ++j)
            b1[q][j] = *(const f16x8*)(w1p[j] + q * 32);

    for (int t = 1; t < TT; ++t) {
        const f16* hcur = hb[(t - 1) & 1];
        f16* hnxt = hb[t & 1];

        // ================= GEMM1: tz = f16(lrelu(z @ W1^T + b1)) =================
        {
            f32x4 ac1[3] = {};
            const float* ap = zf + lm * LZ + k0;
            #pragma unroll
            for (int kk = 0; kk < 16; ++kk) {
                f32x4 x0 = *(const f32x4*)(ap + kk * 32);
                f32x4 x1 = *(const f32x4*)(ap + kk * 32 + 4);
                f16x8 af;
                #pragma unroll
                for (int e = 0; e < 4; ++e) { af[e] = (f16)x0[e]; af[4 + e] = (f16)x1[e]; }
                // use slot kk%3 FIRST ...
                #pragma unroll
                for (int j = 0; j < 3; ++j)
                    ac1[j] = __builtin_amdgcn_mfma_f32_16x16x32_f16(af, b1[kk % 3][j], ac1[j], 0, 0, 0);
                // ... then refill it with fragment kk+3 (indices compile-time via full unroll)
                if (kk + 3 < 16) {
                    #pragma unroll
                    for (int j = 0; j < 3; ++j)
                        b1[kk % 3][j] = *(const f16x8*)(w1p[j] + (kk + 3) * 32);
                }
            }
            #pragma unroll
            for (int j = 0; j < 3; ++j)
                #pragma unroll
                for (int r = 0; r < 4; ++r)
                    tz[(rg0 + r) * LT + c1[j]] = (f16)lrelu(ac1[j][r] + bv1[j]);
        }

        // ---- prime GEMM2/3 pipe (weights only; legal before the barrier) ----
        f16x8 pb[3][7];
        #pragma unroll
        for (int q = 0; q < 3; ++q)
            #pragma unroll
            for (int j = 0; j < 7; ++j)
                pb[q][j] = *(const f16x8*)(wp[j] + q * 32);
        __syncthreads();

        // ======== GEMM2/3 fused: N=896 (4 z-tiles + 3 h-tiles per wave), K=768 ========
        {
            f32x4 ac[7] = {};
            const f16* apz = tz + lm * LT + k0;
            const f16* aph = hcur + lm * LT + k0;
            #pragma unroll
            for (int kk = 0; kk < 24; ++kk) {
                f16x8 af = (kk < 12) ? *(const f16x8*)(apz + kk * 32)
                                     : *(const f16x8*)(aph + (kk - 12) * 32);
                // use slot kk%3 FIRST ...
                #pragma unroll
                for (int j = 0; j < 7; ++j)
                    ac[j] = __builtin_amdgcn_mfma_f32_16x16x32_f16(af, pb[kk % 3][j], ac[j], 0, 0, 0);
                // ... then refill with fragment kk+3
                if (kk + 3 < 24) {
                    #pragma unroll
                    for (int j = 0; j < 7; ++j)
                        pb[kk % 3][j] = *(const f16x8*)(wp[j] + (kk + 3) * 32);
                }
            }

            // ---- epilogue z: zf += v (LDS master) ----
            #pragma unroll
            for (int i = 0; i < 4; ++i)
                #pragma unroll
                for (int r = 0; r < 4; ++r) {
                    int row = rg0 + r;
                    float v = lrelu(ac[i][r] + bvz[i]) * 0.025f;
                    zf[row * LZ + cz[i]] += v;
                }
            // ---- epilogue h: f32 register state, f16 copy for next step ----
            #pragma unroll
            for (int i = 0; i < 3; ++i)
                #pragma unroll
                for (int r = 0; r < 4; ++r) {
                    int row = rg0 + r;
                    float v = lrelu(ac[4 + i][r] + bvh[i]) * 0.025f;
                    hreg[i][r] += v;
                    hnxt[row * LT + ch[i]] = (f16)hreg[i][r];
                }
        }

        // ---- prime next step's GEMM1 pipe (weights static; harmless at t=TT-1) ----
        #pragma unroll
        for (int q = 0; q < 3; ++q)
            #pragma unroll
            for (int j = 0; j < 3; ++j)
                b1[q][j] = *(const f16x8*)(w1p[j] + q * 32);
        __syncthreads();

        // ---- cooperative out store: full 128B lines, out = zf - z0 ----
        for (int i = tid; i < BM * 128; i += 512) {
            int r = i >> 7, c = (i & 127) << 2;
            f32x4 a = *(const f32x4*)(zf + r * LZ + c);
            f32x4 b = *(const f32x4*)(z0c + r * ZD + c);
            f32x4 d = a - b;
            __builtin_nontemporal_store(d,
                (f32x4*)(out + ((size_t)(m0 + r) * TT + t) * ZD + c));
        }
    }
}

extern "C" void kernel_launch(void* const* d_in, const int* in_sizes, int n_in,
                              void* d_out, int out_size, void* d_ws, size_t ws_size,
                              hipStream_t stream) {
    const float* z  = (const float*)d_in[0];
    const float* h0 = (const float*)d_in[1];
    const float* W1 = (const float*)d_in[2];
    const float* b1 = (const float*)d_in[3];
    const float* W2 = (const float*)d_in[4];
    const float* b2 = (const float*)d_in[5];
    const float* W3 = (const float*)d_in[6];
    const float* b3 = (const float*)d_in[7];
    float* out = (float*)d_out;

    char* p = (char*)d_ws;
    f16* W1h = (f16*)p; p += (size_t)HD * ZD * 2;
    f16* W2h = (f16*)p; p += (size_t)ZD * K2 * 2;
    f16* W3h = (f16*)p; p += (size_t)HD * K2 * 2;

    cvt_f32_f16<<<96, 256, 0, stream>>>(W1, W1h, HD * ZD);
    cvt_f32_f16<<<192, 256, 0, stream>>>(W2, W2h, ZD * K2);
    cvt_f32_f16<<<144, 256, 0, stream>>>(W3, W3h, HD * K2);

    latrec<<<4096 / BM, 512, 0, stream>>>(z, h0, W1h, W2h, W3h, b1, b2, b3, out);
}

// Round 6
// 1690.178 us; speedup vs baseline: 1.9105x; 1.9105x over previous
//
#include <hip/hip_runtime.h>
#include <type_traits>

// LatentRecurrent persistent kernel v6: B=4096, Z=512, H=384, T=32, r=0.025
// v2-v5 post-mortem: VGPR_Count pinned at 128 in every variant; 7-tile/wave
// register pipelines exceed the arch-VGPR allocation -> inner-loop scratch
// spills (FETCH 3.4-5.5 GB, MfmaUtil ~3%). v6 restructures instead of tuning:
//   16 waves/block (1024 thr), BM=16, 256 blocks.
//   GEMM1: waves 0-7 tiles {w,w+8}, waves 8-15 tile {w+8}.
//   GEMM2/3 (56 tiles: z 0..31, h 32..55): waves 0-7 {w,w+8,w+16} (3 z),
//     waves 8-15 {u+24,u+32,u+40,u+48} (1 z + 3 h), u=w-8.  ~104/112 MFMA balance.
//   Per-wave live set (<=4 tiles, depth-2 use-then-refill pipe) ~110 regs -> fits
//   the 128-VGPR/4-wave-per-SIMD budget naturally; 4 waves/SIMD TLP covers L2 lat.
// MFMA 16x16x32 f16. A: m=l&15, k=(l>>4)*8+j. B: n=l&15, same k.
// C/D: col=l&15, row=(l>>4)*4+reg   [measured m89]

typedef _Float16 f16;
typedef f16 f16x8 __attribute__((ext_vector_type(8)));
typedef float f32x4 __attribute__((ext_vector_type(4)));

#define ZD 512
#define HD 384
#define K2 768
#define TT 32
#define BM 16
#define TH 1024
#define LZ 516   // zf row stride (f32): 516 % 32 == 4 -> balanced banks
#define LT 392   // tz/hb row stride (f16): 196 words % 32 == 4 -> balanced, 16B rows

__device__ __forceinline__ float lrelu(float x) { return x >= 0.f ? x : 0.01f * x; }

__global__ void cvt_f32_f16(const float* __restrict__ s, f16* __restrict__ d, int n) {
    for (int i = blockIdx.x * blockDim.x + threadIdx.x; i < n; i += gridDim.x * blockDim.x)
        d[i] = (f16)s[i];
}

__global__ __launch_bounds__(TH, 4) void latrec(
    const float* __restrict__ z0g, const float* __restrict__ h0g,
    const f16* __restrict__ W1h, const f16* __restrict__ W2h, const f16* __restrict__ W3h,
    const float* __restrict__ b1g, const float* __restrict__ b2g, const float* __restrict__ b3g,
    float* __restrict__ out)
{
    __shared__ float zf[BM * LZ];      // 33 KB   z master (f32)
    __shared__ float z0c[BM * ZD];     // 32 KB   z0 copy for residual
    __shared__ f16 tz[BM * LT];        // 12.25 KB
    __shared__ f16 hb[2][BM * LT];     // 24.5 KB  -> 101.75 KB, 1 block/CU (16 waves)

    const int tid = threadIdx.x;
    const int w = tid >> 6, l = tid & 63;
    const int lm = l & 15;          // m (A) / n (B) / col (C) within 16-tile
    const int k0 = (l >> 4) * 8;    // k-offset of this lane's fragment
    const int rg0 = (l >> 4) * 4;   // first C/D row of this lane group
    const int m0 = blockIdx.x * BM;
    const bool w8 = (w < 8);

    // ---- init: z into zf + z0c, zero out[:,0,:] ----
    for (int i = tid; i < BM * 128; i += TH) {
        int r = i >> 7, c = (i & 127) << 2;
        f32x4 v = *(const f32x4*)(z0g + (size_t)(m0 + r) * ZD + c);
        *(f32x4*)(zf + r * LZ + c) = v;
        *(f32x4*)(z0c + r * ZD + c) = v;
        f32x4 zr = {0.f, 0.f, 0.f, 0.f};
        __builtin_nontemporal_store(zr, (f32x4*)(out + (size_t)(m0 + r) * TT * ZD + c));
    }
    // ---- hb[0] init (cooperative) ----
    for (int i = tid; i < BM * HD; i += TH) {
        int r = i / HD, c = i - r * HD;
        hb[0][r * LT + c] = (f16)h0g[(size_t)(m0 + r) * HD + c];
    }

    // ---- per-wave tile setup ----
    // GEMM1
    int c1[2]; float bv1[2]; const f16* w1p[2];
    c1[0] = ((w8 ? w : w + 8) * 16) + lm;
    c1[1] = w8 ? ((w + 8) * 16 + lm) : c1[0];
    bv1[0] = b1g[c1[0]]; bv1[1] = b1g[c1[1]];
    w1p[0] = W1h + (size_t)c1[0] * ZD + k0;
    w1p[1] = W1h + (size_t)c1[1] * ZD + k0;
    // GEMM2/3
    int tl[4];
    if (w8) { tl[0] = w; tl[1] = w + 8; tl[2] = w + 16; tl[3] = w + 16; }
    else { int u = w - 8; tl[0] = u + 24; tl[1] = u + 32; tl[2] = u + 40; tl[3] = u + 48; }
    int c2[4]; float bv2[4]; const f16* wp[4];
    float hreg[4][4];
    #pragma unroll
    for (int j = 0; j < 4; ++j) {
        bool isz = tl[j] < 32;
        int cc = (isz ? tl[j] : tl[j] - 32) * 16 + lm;
        c2[j] = cc;
        bv2[j] = isz ? b2g[cc] : b3g[cc];
        wp[j] = (isz ? W2h : W3h) + (size_t)cc * K2 + k0;
        if (!isz) {
            #pragma unroll
            for (int r = 0; r < 4; ++r)
                hreg[j][r] = h0g[(size_t)(m0 + rg0 + r) * HD + cc];
        }
    }
    __syncthreads();

    for (int t = 1; t < TT; ++t) {
        const f16* hcur = hb[(t - 1) & 1];
        f16* hnxt = hb[t & 1];

        // ================= GEMM1: tz = f16(lrelu(z @ W1^T + b1)) =================
        {
            const float* ap = zf + lm * LZ + k0;
            auto run1 = [&](auto N1C) {
                constexpr int N1 = decltype(N1C)::value;
                f32x4 ac1[N1] = {};
                f16x8 p1[2][N1];
                #pragma unroll
                for (int q = 0; q < 2; ++q)
                    #pragma unroll
                    for (int j = 0; j < N1; ++j)
                        p1[q][j] = *(const f16x8*)(w1p[j] + q * 32);
                #pragma unroll
                for (int kk = 0; kk < 16; ++kk) {
                    f32x4 x0 = *(const f32x4*)(ap + kk * 32);
                    f32x4 x1 = *(const f32x4*)(ap + kk * 32 + 4);
                    f16x8 af;
                    #pragma unroll
                    for (int e = 0; e < 4; ++e) { af[e] = (f16)x0[e]; af[4 + e] = (f16)x1[e]; }
                    #pragma unroll
                    for (int j = 0; j < N1; ++j)
                        ac1[j] = __builtin_amdgcn_mfma_f32_16x16x32_f16(af, p1[kk & 1][j], ac1[j], 0, 0, 0);
                    if (kk + 2 < 16) {               // use-then-refill (WAR-safe)
                        #pragma unroll
                        for (int j = 0; j < N1; ++j)
                            p1[kk & 1][j] = *(const f16x8*)(w1p[j] + (kk + 2) * 32);
                    }
                }
                #pragma unroll
                for (int j = 0; j < N1; ++j)
                    #pragma unroll
                    for (int r = 0; r < 4; ++r)
                        tz[(rg0 + r) * LT + c1[j]] = (f16)lrelu(ac1[j][r] + bv1[j]);
            };
            if (w8) run1(std::integral_constant<int, 2>{});
            else    run1(std::integral_constant<int, 1>{});
        }
        __syncthreads();

        // ======== GEMM2/3 fused: K=768 (tz then hcur), per-wave 3-4 N-tiles ========
        {
            const f16* apz = tz + lm * LT + k0;
            const f16* aph = hcur + lm * LT + k0;
            auto run2 = [&](auto NTC, auto ZALLC) {
                constexpr int NT = decltype(NTC)::value;
                constexpr bool ZALL = decltype(ZALLC)::value;
                f32x4 ac[NT] = {};
                f16x8 pb[2][NT];
                #pragma unroll
                for (int q = 0; q < 2; ++q)
                    #pragma unroll
                    for (int j = 0; j < NT; ++j)
                        pb[q][j] = *(const f16x8*)(wp[j] + q * 32);
                #pragma unroll
                for (int kk = 0; kk < 24; ++kk) {
                    f16x8 af = (kk < 12) ? *(const f16x8*)(apz + kk * 32)
                                         : *(const f16x8*)(aph + (kk - 12) * 32);
                    #pragma unroll
                    for (int j = 0; j < NT; ++j)
                        ac[j] = __builtin_amdgcn_mfma_f32_16x16x32_f16(af, pb[kk & 1][j], ac[j], 0, 0, 0);
                    if (kk + 2 < 24) {               // use-then-refill (WAR-safe)
                        #pragma unroll
                        for (int j = 0; j < NT; ++j)
                            pb[kk & 1][j] = *(const f16x8*)(wp[j] + (kk + 2) * 32);
                    }
                }
                // ---- epilogue ----
                #pragma unroll
                for (int j = 0; j < NT; ++j) {
                    if (ZALL || j == 0) {            // z tile: zf += v
                        #pragma unroll
                        for (int r = 0; r < 4; ++r) {
                            int row = rg0 + r;
                            float v = lrelu(ac[j][r] + bv2[j]) * 0.025f;
                            zf[row * LZ + c2[j]] += v;
                        }
                    } else {                          // h tile: hreg += v, write hnxt
                        #pragma unroll
                        for (int r = 0; r < 4; ++r) {
                            int row = rg0 + r;
                            float v = lrelu(ac[j][r] + bv2[j]) * 0.025f;
                            hreg[j][r] += v;
                            hnxt[row * LT + c2[j]] = (f16)hreg[j][r];
                        }
                    }
                }
            };
            if (w8) run2(std::integral_constant<int, 3>{}, std::true_type{});
            else    run2(std::integral_constant<int, 4>{}, std::false_type{});
        }
        __syncthreads();

        // ---- cooperative out store: full 128B lines, out = zf - z0 ----
        for (int i = tid; i < BM * 128; i += TH) {
            int r = i >> 7, c = (i & 127) << 2;
            f32x4 a = *(const f32x4*)(zf + r * LZ + c);
            f32x4 b = *(const f32x4*)(z0c + r * ZD + c);
            f32x4 d = a - b;
            __builtin_nontemporal_store(d,
                (f32x4*)(out + ((size_t)(m0 + r) * TT + t) * ZD + c));
        }
    }
}

extern "C" void kernel_launch(void* const* d_in, const int* in_sizes, int n_in,
                              void* d_out, int out_size, void* d_ws, size_t ws_size,
                              hipStream_t stream) {
    const float* z  = (const float*)d_in[0];
    const float* h0 = (const float*)d_in[1];
    const float* W1 = (const float*)d_in[2];
    const float* b1 = (const float*)d_in[3];
    const float* W2 = (const float*)d_in[4];
    const float* b2 = (const float*)d_in[5];
    const float* W3 = (const float*)d_in[6];
    const float* b3 = (const float*)d_in[7];
    float* out = (float*)d_out;

    char* p = (char*)d_ws;
    f16* W1h = (f16*)p; p += (size_t)HD * ZD * 2;
    f16* W2h = (f16*)p; p += (size_t)ZD * K2 * 2;
    f16* W3h = (f16*)p; p += (size_t)HD * K2 * 2;

    cvt_f32_f16<<<96, 256, 0, stream>>>(W1, W1h, HD * ZD);
    cvt_f32_f16<<<192, 256, 0, stream>>>(W2, W2h, ZD * K2);
    cvt_f32_f16<<<144, 256, 0, stream>>>(W3, W3h, HD * K2);

    latrec<<<4096 / BM, TH, 0, stream>>>(z, h0, W1h, W2h, W3h, b1, b2, b3, out);
}